// Round 1
// baseline (711.373 us; speedup 1.0000x reference)
//
#include <hip/hip_runtime.h>
#include <hip/hip_bf16.h>
#include <math.h>

// Problem constants
#define B_    8
#define NT_   1024
#define DIM_  768
#define H_    12
#define HD_   64
#define SCALE_ 0.125f

typedef _Float16 half8  __attribute__((ext_vector_type(8)));
typedef float    floatx4 __attribute__((ext_vector_type(4)));

// ---------------------------------------------------------------- conversion
__global__ void cvt_f32_f16(const float* __restrict__ in,
                            _Float16* __restrict__ out, int n) {
  int i = blockIdx.x * 256 + threadIdx.x;
  if (i < n) out[i] = (_Float16)in[i];
}

// ---------------------------------------------------------------- GEMM
// C[m][n] = sum_k A[m][k] * Bt[n][k] + bias[n]
// A: MxK fp16 row-major, Bt: NxK fp16 row-major (i.e. y = x @ W^T, W=[out,in])
// 256 threads = 4 waves (2x2), block tile 64x64, BK=32.
template<bool F32OUT>
__global__ __launch_bounds__(256) void gemm_bt(
    const _Float16* __restrict__ A, const _Float16* __restrict__ Bt,
    const float* __restrict__ bias, _Float16* __restrict__ outh,
    float* __restrict__ outf, int M, int N, int K)
{
  __shared__ _Float16 As[64][40];  // 64 rows x 32 k (+8 pad, keeps 16B align)
  __shared__ _Float16 Bs[64][40];
  const int t    = threadIdx.x;
  const int w    = t >> 6, lane = t & 63;
  const int quad = lane >> 4, l16 = lane & 15;
  const int wm   = (w >> 1) * 32, wn = (w & 1) * 32;
  const int m0   = blockIdx.x * 64, n0 = blockIdx.y * 64;
  const int lrow = t >> 2, lcol = (t & 3) * 8;

  floatx4 acc[2][2] = {};

  for (int k0 = 0; k0 < K; k0 += 32) {
    uint4 av = *(const uint4*)(A  + (size_t)(m0 + lrow) * K + k0 + lcol);
    uint4 bv = *(const uint4*)(Bt + (size_t)(n0 + lrow) * K + k0 + lcol);
    __syncthreads();
    *(uint4*)(&As[lrow][lcol]) = av;
    *(uint4*)(&Bs[lrow][lcol]) = bv;
    __syncthreads();
    // A frag: m = lane&15, k = quad*8 + j ; B frag: n = lane&15, k = quad*8 + j
    half8 a0 = *(const half8*)(&As[wm      + l16][quad * 8]);
    half8 a1 = *(const half8*)(&As[wm + 16 + l16][quad * 8]);
    half8 b0 = *(const half8*)(&Bs[wn      + l16][quad * 8]);
    half8 b1 = *(const half8*)(&Bs[wn + 16 + l16][quad * 8]);
    acc[0][0] = __builtin_amdgcn_mfma_f32_16x16x32_f16(a0, b0, acc[0][0], 0, 0, 0);
    acc[0][1] = __builtin_amdgcn_mfma_f32_16x16x32_f16(a0, b1, acc[0][1], 0, 0, 0);
    acc[1][0] = __builtin_amdgcn_mfma_f32_16x16x32_f16(a1, b0, acc[1][0], 0, 0, 0);
    acc[1][1] = __builtin_amdgcn_mfma_f32_16x16x32_f16(a1, b1, acc[1][1], 0, 0, 0);
  }

  // C/D layout: row = quad*4 + reg, col = lane&15   [measured m89/m91]
  for (int i = 0; i < 2; i++)
    for (int j = 0; j < 2; j++)
      for (int r = 0; r < 4; r++) {
        int row = m0 + wm + i * 16 + quad * 4 + r;
        int col = n0 + wn + j * 16 + l16;
        float v = acc[i][j][r] + bias[col];
        if (F32OUT) outf[(size_t)row * N + col] = v;
        else        outh[(size_t)row * N + col] = (_Float16)v;
      }
}

// ---------------------------------------------------------------- attention
// One block per (qtile=64 rows, h, b). 256 threads = 4 waves; wave w owns
// q-rows [w*16, w*16+16). Two-pass exact softmax:
//   pass 1: streaming row-max m and row-sum l over all 1024 keys
//   pass 2: recompute S, p = exp(s-m)/l -> write attn (fp32, d_out) and
//           accumulate O += P @ V via MFMA (P round-trips through LDS to
//           convert C/D layout -> A-operand layout).
__global__ __launch_bounds__(256) void attn_kernel(
    const _Float16* __restrict__ Qh, const _Float16* __restrict__ Kh,
    const _Float16* __restrict__ Vh, float* __restrict__ attn_out,
    _Float16* __restrict__ Xh)
{
  __shared__ _Float16 Qs[64][72];
  __shared__ _Float16 Ks[64][72];
  __shared__ _Float16 Vt[64][72];  // transposed: [d][key]
  __shared__ _Float16 Ps[64][72];  // probs in A-layout source: [q_local][key]

  const int t    = threadIdx.x;
  const int w    = t >> 6, lane = t & 63;
  const int quad = lane >> 4, l16 = lane & 15;
  const int qt = blockIdx.x, h = blockIdx.y, b = blockIdx.z;
  const int q0 = qt * 64;

  const _Float16* Qb = Qh + ((size_t)b * NT_) * DIM_ + h * HD_;
  const _Float16* Kb = Kh + ((size_t)b * NT_) * DIM_ + h * HD_;
  const _Float16* Vb = Vh + ((size_t)b * NT_) * DIM_ + h * HD_;

  const int lrow = t >> 2;          // 0..63
  const int lcol = (t & 3) * 16;    // 0,16,32,48 : 16 halves per thread

  // load Q tile (64 x 64)
  *(uint4*)(&Qs[lrow][lcol])     = *(const uint4*)(Qb + (size_t)(q0 + lrow) * DIM_ + lcol);
  *(uint4*)(&Qs[lrow][lcol + 8]) = *(const uint4*)(Qb + (size_t)(q0 + lrow) * DIM_ + lcol + 8);

  float m_run[4], l_run[4];
#pragma unroll
  for (int r = 0; r < 4; r++) { m_run[r] = -INFINITY; l_run[r] = 0.0f; }

  // ---------------- pass 1: row max / sum
  for (int kt = 0; kt < 16; kt++) {
    __syncthreads();
    *(uint4*)(&Ks[lrow][lcol])     = *(const uint4*)(Kb + (size_t)(kt * 64 + lrow) * DIM_ + lcol);
    *(uint4*)(&Ks[lrow][lcol + 8]) = *(const uint4*)(Kb + (size_t)(kt * 64 + lrow) * DIM_ + lcol + 8);
    __syncthreads();

    floatx4 s[4] = {};
#pragma unroll
    for (int ks = 0; ks < 2; ks++) {
      half8 a = *(const half8*)(&Qs[w * 16 + l16][ks * 32 + quad * 8]);
#pragma unroll
      for (int j = 0; j < 4; j++) {
        half8 bk = *(const half8*)(&Ks[j * 16 + l16][ks * 32 + quad * 8]);
        s[j] = __builtin_amdgcn_mfma_f32_16x16x32_f16(a, bk, s[j], 0, 0, 0);
      }
    }
#pragma unroll
    for (int r = 0; r < 4; r++) {
      float tm = -INFINITY;
#pragma unroll
      for (int j = 0; j < 4; j++) tm = fmaxf(tm, s[j][r] * SCALE_);
      for (int off = 1; off < 16; off <<= 1)
        tm = fmaxf(tm, __shfl_xor(tm, off, 64));
      float nm = fmaxf(m_run[r], tm);
      float ts = 0.0f;
#pragma unroll
      for (int j = 0; j < 4; j++) ts += expf(s[j][r] * SCALE_ - nm);
      for (int off = 1; off < 16; off <<= 1)
        ts += __shfl_xor(ts, off, 64);
      l_run[r] = l_run[r] * expf(m_run[r] - nm) + ts;
      m_run[r] = nm;
    }
  }

  float inv_l[4];
#pragma unroll
  for (int r = 0; r < 4; r++) inv_l[r] = 1.0f / l_run[r];

  // ---------------- pass 2: probs out + O = P @ V
  floatx4 oacc[4] = {};
  float* attn_b = attn_out + ((size_t)(b * H_ + h) * NT_ + q0) * NT_;

  for (int kt = 0; kt < 16; kt++) {
    __syncthreads();
    *(uint4*)(&Ks[lrow][lcol])     = *(const uint4*)(Kb + (size_t)(kt * 64 + lrow) * DIM_ + lcol);
    *(uint4*)(&Ks[lrow][lcol + 8]) = *(const uint4*)(Kb + (size_t)(kt * 64 + lrow) * DIM_ + lcol + 8);
    {
      alignas(16) _Float16 vh[16];
      *(uint4*)(vh)     = *(const uint4*)(Vb + (size_t)(kt * 64 + lrow) * DIM_ + lcol);
      *(uint4*)(vh + 8) = *(const uint4*)(Vb + (size_t)(kt * 64 + lrow) * DIM_ + lcol + 8);
#pragma unroll
      for (int c = 0; c < 16; c++) Vt[lcol + c][lrow] = vh[c];
    }
    __syncthreads();

    // recompute S (identical to pass 1 -> consistent m,l)
    floatx4 s[4] = {};
#pragma unroll
    for (int ks = 0; ks < 2; ks++) {
      half8 a = *(const half8*)(&Qs[w * 16 + l16][ks * 32 + quad * 8]);
#pragma unroll
      for (int j = 0; j < 4; j++) {
        half8 bk = *(const half8*)(&Ks[j * 16 + l16][ks * 32 + quad * 8]);
        s[j] = __builtin_amdgcn_mfma_f32_16x16x32_f16(a, bk, s[j], 0, 0, 0);
      }
    }

    // normalize, write attn (fp32), stage P (fp16) for PV
#pragma unroll
    for (int j = 0; j < 4; j++)
#pragma unroll
      for (int r = 0; r < 4; r++) {
        float p = expf(s[j][r] * SCALE_ - m_run[r]) * inv_l[r];
        int qr = w * 16 + quad * 4 + r;              // local q row
        attn_b[(size_t)qr * NT_ + kt * 64 + j * 16 + l16] = p;
        Ps[qr][j * 16 + l16] = (_Float16)p;
      }
    // Ps rows [w*16, w*16+16) are written AND read only by wave w -> no
    // __syncthreads needed (compiler inserts lgkmcnt waits).

#pragma unroll
    for (int ks = 0; ks < 2; ks++) {
      half8 pa = *(const half8*)(&Ps[w * 16 + l16][ks * 32 + quad * 8]);
#pragma unroll
      for (int j2 = 0; j2 < 4; j2++) {
        half8 bv = *(const half8*)(&Vt[j2 * 16 + l16][ks * 32 + quad * 8]);
        oacc[j2] = __builtin_amdgcn_mfma_f32_16x16x32_f16(pa, bv, oacc[j2], 0, 0, 0);
      }
    }
  }

  // write X (fp16, [B,NT,DIM] with head offset) for the output projection
#pragma unroll
  for (int j2 = 0; j2 < 4; j2++)
#pragma unroll
    for (int r = 0; r < 4; r++) {
      int qr = q0 + w * 16 + quad * 4 + r;
      Xh[((size_t)b * NT_ + qr) * DIM_ + h * HD_ + j2 * 16 + l16] = (_Float16)oacc[j2][r];
    }
}

// ---------------------------------------------------------------- launch
extern "C" void kernel_launch(void* const* d_in, const int* in_sizes, int n_in,
                              void* d_out, int out_size, void* d_ws, size_t ws_size,
                              hipStream_t stream) {
  const float* tfeat = (const float*)d_in[0];
  const float* wq    = (const float*)d_in[1];
  const float* bq    = (const float*)d_in[2];
  const float* wk    = (const float*)d_in[3];
  const float* bk    = (const float*)d_in[4];
  const float* wv    = (const float*)d_in[5];
  const float* bv    = (const float*)d_in[6];
  const float* wp    = (const float*)d_in[7];
  const float* bp    = (const float*)d_in[8];
  float* out = (float*)d_out;

  const size_t T = (size_t)B_ * NT_ * DIM_;   // 6,291,456
  const size_t W = (size_t)DIM_ * DIM_;       // 589,824

  _Float16* ws  = (_Float16*)d_ws;
  _Float16* tfh = ws;
  _Float16* wqh = ws + T;
  _Float16* wkh = ws + T + W;
  _Float16* wvh = ws + T + 2 * W;
  _Float16* wph = ws + T + 3 * W;
  _Float16* Qh  = ws + T + 4 * W;
  _Float16* Kh  = Qh + T;
  _Float16* Vh  = Kh + T;
  _Float16* Xh  = Vh + T;

  cvt_f32_f16<<<(int)((T + 255) / 256), 256, 0, stream>>>(tfeat, tfh, (int)T);
  cvt_f32_f16<<<(int)((W + 255) / 256), 256, 0, stream>>>(wq, wqh, (int)W);
  cvt_f32_f16<<<(int)((W + 255) / 256), 256, 0, stream>>>(wk, wkh, (int)W);
  cvt_f32_f16<<<(int)((W + 255) / 256), 256, 0, stream>>>(wv, wvh, (int)W);
  cvt_f32_f16<<<(int)((W + 255) / 256), 256, 0, stream>>>(wp, wph, (int)W);

  dim3 gg(8192 / 64, 768 / 64);  // (128, 12)
  gemm_bt<false><<<gg, 256, 0, stream>>>(tfh, wqh, bq, Qh, nullptr, 8192, 768, 768);
  gemm_bt<false><<<gg, 256, 0, stream>>>(tfh, wkh, bk, Kh, nullptr, 8192, 768, 768);
  gemm_bt<false><<<gg, 256, 0, stream>>>(tfh, wvh, bv, Vh, nullptr, 8192, 768, 768);

  attn_kernel<<<dim3(NT_ / 64, H_, B_), 256, 0, stream>>>(Qh, Kh, Vh, out + T, Xh);

  gemm_bt<true><<<gg, 256, 0, stream>>>(Xh, wph, bp, nullptr, out, 8192, 768, 768);
}